// Round 12
// baseline (762.023 us; speedup 1.0000x reference)
//
#include <hip/hip_runtime.h>
#include <hip/hip_fp16.h>
#include <math.h>

constexpr int NN   = 50000;
constexpr int NE   = 800000;
constexpr int NREL = 4;
constexpr int NB   = (NN + 255) / 256;   // scan blocks

typedef _Float16 half8 __attribute__((ext_vector_type(8)));   // 8 fp16 (4 VGPRs)
typedef __attribute__((ext_vector_type(4))) float floatx4;    // MFMA acc

__device__ inline unsigned short f16_rne(float x) {
  return __half_as_ushort(__float2half_rn(x));
}
__device__ inline float h2f(unsigned short h) {
  return __half2float(__ushort_as_half(h));
}

// ---------------------------------------------------------------------------
__global__ void k_counts(const int* __restrict__ dst, const int* __restrict__ et,
                         int* cntrel) {
  int e = blockIdx.x * blockDim.x + threadIdx.x;
  if (e < NE) {
    int d = dst[e];
    atomicAdd(&cntrel[d * NREL + et[e]], 1);
  }
}

__global__ void k_scan1(const int* __restrict__ cntrel, int* bsum) {
  __shared__ int sm[256];
  int i = blockIdx.x * 256 + threadIdx.x;
  int v = 0;
  if (i < NN) { int4 c = ((const int4*)cntrel)[i]; v = c.x + c.y + c.z + c.w; }
  sm[threadIdx.x] = v;
  __syncthreads();
  for (int s = 128; s; s >>= 1) {
    if (threadIdx.x < s) sm[threadIdx.x] += sm[threadIdx.x + s];
    __syncthreads();
  }
  if (threadIdx.x == 0) bsum[blockIdx.x] = sm[0];
}
__global__ void k_scan2(const int* __restrict__ bsum, int* boff, int* rowptr) {
  if (threadIdx.x == 0 && blockIdx.x == 0) {
    int acc = 0;
    for (int b = 0; b < NB; ++b) { boff[b] = acc; acc += bsum[b]; }
    rowptr[NN] = NE;
  }
}
__global__ void k_scan3(const int* __restrict__ cntrel, const int* __restrict__ boff,
                        int* rowptr) {
  __shared__ int sm[256];
  int i = blockIdx.x * 256 + threadIdx.x;
  int v = 0;
  if (i < NN) { int4 c = ((const int4*)cntrel)[i]; v = c.x + c.y + c.z + c.w; }
  sm[threadIdx.x] = v;
  __syncthreads();
  for (int s = 1; s < 256; s <<= 1) {
    int t = (threadIdx.x >= s) ? sm[threadIdx.x - s] : 0;
    __syncthreads();
    sm[threadIdx.x] += t;
    __syncthreads();
  }
  if (i < NN) rowptr[i] = boff[blockIdx.x] + sm[threadIdx.x] - v;  // exclusive
}

__global__ void k_fill(const int* __restrict__ src, const int* __restrict__ dst,
                       const int* __restrict__ et, const int* __restrict__ rowptr,
                       int* cursor, int* srcs, int* ets) {
  int e = blockIdx.x * blockDim.x + threadIdx.x;
  if (e >= NE) return;
  int d = dst[e];
  int pos = rowptr[d] + atomicAdd(&cursor[d], 1);
  srcs[pos] = src[e];
  ets[pos]  = et[e];
}

// ---------------------------------------------------------------------------
// weight packing into MFMA fragment order, single fp16 plane (2^-11 rel err).
#define PK_N 14
__device__ __constant__ const int PK_BASE[PK_N]  = {0,1,2,3,4,4,5,5,5,5,6,7,7,7};
__device__ __constant__ const int PK_EOFF[PK_N]  = {0,0,0,0,0,256,0,32768,65536,98304,0,0,32768,65536};
__device__ __constant__ const int PK_K[PK_N]     = {128,128,256,256,256,256,256,256,256,256,256,256,256,128};
__device__ __constant__ const int PK_LDB[PK_N]   = {256,256,256,256,512,512,128,128,128,128,128,128,128,128};
__device__ __constant__ const int PK_START[PK_N] = {0,4096,8192,16384,24576,32768,40960,45056,49152,53248,57344,61440,65536,69632};
constexpr int PK_TOTAL = 71680;
constexpr int BF_S1WL = 0,     BF_S1WR = 4096,  BF_S2WL = 8192,  BF_S2WR = 16384;
constexpr int BF_GATW0 = 24576, BF_GATW1 = 32768, BF_WREL = 40960, BF_WROOT = 57344;
constexpr int BF_FW0 = 61440,  BF_FW1 = 65536,  BF_FW2 = 69632;

__global__ void k_pack(const float* b0, const float* b1, const float* b2, const float* b3,
                       const float* b4, const float* b5, const float* b6, const float* b7,
                       unsigned short* __restrict__ Bh) {
  int f = blockIdx.x * 256 + threadIdx.x;
  if (f >= PK_TOTAL) return;
  int m = 0;
#pragma unroll
  for (int i = 1; i < PK_N; ++i) if (f >= PK_START[i]) m = i;
  const float* bases[8] = {b0,b1,b2,b3,b4,b5,b6,b7};
  int lf = f - PK_START[m];
  int K = PK_K[m], ldb = PK_LDB[m];
  int Kq16 = K << 1;
  int ntile = lf / Kq16;
  int rem = lf - ntile * Kq16;
  int kq = rem >> 4, c = rem & 15;
  const float* sp = bases[PK_BASE[m]] + PK_EOFF[m] + (size_t)(kq * 8) * ldb + ntile * 16 + c;
#pragma unroll
  for (int j = 0; j < 8; ++j)
    Bh[(size_t)f * 8 + j] = f16_rne(sp[(size_t)j * ldb]);
}

// x -> fp16 plane
__global__ void k_split(const float* __restrict__ x, unsigned short* __restrict__ xh,
                        long total4) {
  long i = (long)blockIdx.x * blockDim.x + threadIdx.x;
  if (i >= total4) return;
  float4 v = ((const float4*)x)[i];
  ushort4 h;
  h.x = f16_rne(v.x); h.y = f16_rne(v.y);
  h.z = f16_rne(v.z); h.w = f16_rne(v.w);
  ((ushort4*)xh)[i] = h;
}

// ---------------------------------------------------------------------------
// CSR mean, 128 ch. [R9-proven form] 1 wave/node, 4-way unrolled gather.
__global__ void k_mean128p(const unsigned short* __restrict__ ih, const int* __restrict__ rowptr,
                           const int* __restrict__ srcs,
                           unsigned short* __restrict__ oh) {
  int node = blockIdx.x * 4 + (threadIdx.x >> 6);
  int lane = threadIdx.x & 63;
  if (node >= NN) return;
  int p0 = rowptr[node], p1 = rowptr[node + 1];
  float2 acc = make_float2(0.f, 0.f);
  int p = p0;
  for (; p + 4 <= p1; p += 4) {
    int s0 = srcs[p], s1 = srcs[p+1], s2 = srcs[p+2], s3 = srcs[p+3];
    ushort2 v0 = ((const ushort2*)(ih + ((size_t)s0 << 7)))[lane];
    ushort2 v1 = ((const ushort2*)(ih + ((size_t)s1 << 7)))[lane];
    ushort2 v2 = ((const ushort2*)(ih + ((size_t)s2 << 7)))[lane];
    ushort2 v3 = ((const ushort2*)(ih + ((size_t)s3 << 7)))[lane];
    acc.x += (h2f(v0.x) + h2f(v1.x)) + (h2f(v2.x) + h2f(v3.x));
    acc.y += (h2f(v0.y) + h2f(v1.y)) + (h2f(v2.y) + h2f(v3.y));
  }
  for (; p < p1; ++p) {
    int s = srcs[p];
    ushort2 hv = ((const ushort2*)(ih + ((size_t)s << 7)))[lane];
    acc.x += h2f(hv.x); acc.y += h2f(hv.y);
  }
  float inv = (p1 > p0) ? 1.0f / (float)(p1 - p0) : 0.0f;
  ushort2 h;
  h.x = f16_rne(acc.x * inv); h.y = f16_rne(acc.y * inv);
  size_t o = ((size_t)node << 7) + lane * 2;
  *(ushort2*)(oh + o) = h;
}

// CSR mean, 256 ch. [R9-proven form] 1 wave/node, 8-way unrolled gather.
__global__ void k_mean256p(const unsigned short* __restrict__ ih, const int* __restrict__ rowptr,
                           const int* __restrict__ srcs,
                           unsigned short* __restrict__ oh) {
  int node = blockIdx.x * 4 + (threadIdx.x >> 6);
  int lane = threadIdx.x & 63;
  if (node >= NN) return;
  int p0 = rowptr[node], p1 = rowptr[node + 1];
  float4 acc = make_float4(0.f, 0.f, 0.f, 0.f);
  int p = p0;
  for (; p + 8 <= p1; p += 8) {
    int ss[8]; ushort4 xr[8];
#pragma unroll
    for (int j = 0; j < 8; ++j) ss[j] = srcs[p + j];
#pragma unroll
    for (int j = 0; j < 8; ++j)
      xr[j] = *(const ushort4*)(ih + ((size_t)ss[j] << 8) + lane * 4);
#pragma unroll
    for (int j = 0; j < 8; ++j) {
      acc.x += h2f(xr[j].x); acc.y += h2f(xr[j].y);
      acc.z += h2f(xr[j].z); acc.w += h2f(xr[j].w);
    }
  }
  for (; p < p1; ++p) {
    int s = srcs[p];
    ushort4 hv = *(const ushort4*)(ih + ((size_t)s << 8) + lane * 4);
    acc.x += h2f(hv.x); acc.y += h2f(hv.y);
    acc.z += h2f(hv.z); acc.w += h2f(hv.w);
  }
  float inv = (p1 > p0) ? 1.0f / (float)(p1 - p0) : 0.0f;
  ushort4 h;
  h.x = f16_rne(acc.x * inv); h.y = f16_rne(acc.y * inv);
  h.z = f16_rne(acc.z * inv); h.w = f16_rne(acc.w * inv);
  size_t o = ((size_t)node << 8) + lane * 4;
  *(ushort4*)(oh + o) = h;
}

// ---------------------------------------------------------------------------
// fp16 MFMA GEMM, LDS-FREE. [R12] The old LDS staging was an identity
// permutation: each wave's fragments are directly loadable from global —
//   A frag (mt,lane) = A[row0+(wm*4+mt)*16+(lane&15)][kt+(lane>>4)*8..+8]
//     (16 fully-consumed 64B cachelines per wave-load), and
//   B frag (nt,lane) = Bph[(bf+(col0/16+wn*4+nt)*Kq16 + kt*2 + lane)*8]
//     (contiguous/coalesced: B is pre-packed in fragment order).
// Zero LDS, zero barriers -> compiler pipelines loads across K freely
// (removes the vmcnt(0)+barrier drain of the staged structure).
// OOB rows clamp to M-1 (finite garbage, never stored; >=12MB slab slack).
// XCD-chunked bijective block swizzle (T1/m204) for A-stripe L2 reuse.
// xtmode=2 (fused RGCN): cols<512 -> xth[c>>7][row][c&127] fp16 scatter;
//                        cols>=512 -> P3f[row][c&127] f32 + bias.
__global__ __launch_bounds__(256)
void k_gemm_mfma(const unsigned short* __restrict__ Bph,
                 const unsigned short* A0, int lda0, int bf0, int K0,
                 const unsigned short* A1, int lda1, int bf1, int K1,
                 const unsigned short* A2, int lda2, int bf2, int K2,
                 const float* __restrict__ bias, float* Cf, unsigned short* Ch,
                 int M, int Nc, float scale, int do_relu, int xtmode)
{
  const int tid  = threadIdx.x;
  const int lane = tid & 63;
  const int wv   = tid >> 6;
  const int wm   = wv >> 1, wn = wv & 1;
  // bijective XCD-chunked swizzle over the x-y grid
  const int nwg = gridDim.x * gridDim.y;
  const int d   = blockIdx.x + gridDim.x * blockIdx.y;
  const int q   = nwg >> 3, r = nwg & 7;
  const int xcd = d & 7, di = d >> 3;
  const int wg  = (xcd < r ? xcd * (q + 1) : r * (q + 1) + (xcd - r) * q) + di;
  const int row0 = (wg / gridDim.x) * 128;
  const int col0 = (wg % gridDim.x) * 128;

  const int c15 = lane & 15;
  const int k8  = (lane >> 4) * 8;

  floatx4 acc[4][4];
#pragma unroll
  for (int i = 0; i < 4; ++i)
#pragma unroll
    for (int j = 0; j < 4; ++j) acc[i][j] = 0;

  const unsigned short* Aarr[3] = {A0, A1, A2};
  const int ldaArr[3] = {lda0, lda1, lda2};
  const int bfArr[3]  = {bf0, bf1, bf2};
  const int Karr[3]   = {K0, K1, K2};

  for (int p = 0; p < 3; ++p) {
    const int K = Karr[p];
    if (K == 0) continue;
    const int lda = ldaArr[p];
    const int Kq16 = K << 1;
    // per-lane A row pointers (row clamped to M-1: OOB rows contribute only
    // to acc rows never stored)
    const unsigned short* Arow[4];
#pragma unroll
    for (int mt = 0; mt < 4; ++mt) {
      int row = row0 + (wm * 4 + mt) * 16 + c15;
      if (row > M - 1) row = M - 1;
      Arow[mt] = Aarr[p] + (size_t)row * lda + k8;
    }
    // per-lane B fragment pointers
    const unsigned short* Brow[4];
#pragma unroll
    for (int nt = 0; nt < 4; ++nt)
      Brow[nt] = Bph + (size_t)(bfArr[p] + ((col0 >> 4) + wn * 4 + nt) * Kq16 + lane) * 8;

#pragma unroll 2
    for (int kt = 0; kt < K; kt += 32) {
      half8 af[4], bfq[4];
#pragma unroll
      for (int mt = 0; mt < 4; ++mt)
        af[mt] = *(const half8*)(const void*)(Arow[mt] + kt);
#pragma unroll
      for (int nt = 0; nt < 4; ++nt)
        bfq[nt] = *(const half8*)(const void*)(Brow[nt] + (size_t)(kt << 1) * 8);
#pragma unroll
      for (int mt = 0; mt < 4; ++mt)
#pragma unroll
        for (int nt = 0; nt < 4; ++nt)
          acc[mt][nt] = __builtin_amdgcn_mfma_f32_16x16x32_f16(af[mt], bfq[nt], acc[mt][nt], 0, 0, 0);
    }
  }

  // epilogue: C/D layout col=lane&15, row=(lane>>4)*4+reg   [m89-verified]
  const int cl = lane & 15;
  const int rq = lane >> 4;
#pragma unroll
  for (int mt = 0; mt < 4; ++mt)
#pragma unroll
    for (int r2 = 0; r2 < 4; ++r2) {
      int row = row0 + wm * 64 + mt * 16 + rq * 4 + r2;
      if (row < M) {
#pragma unroll
        for (int nt = 0; nt < 4; ++nt) {
          int colx = col0 + wn * 64 + nt * 16 + cl;
          float vraw = acc[mt][nt][r2] * scale;
          if (xtmode == 2) {
            // fused RGCN: WREL cols [0,512) scatter to xth; WROOT cols [512,640) -> P3f
            if (colx < 512) {
              size_t o = (size_t)(colx >> 7) * ((size_t)NN * 128) + (size_t)row * 128 + (colx & 127);
              Ch[o] = f16_rne(vraw);
            } else {
              size_t o = (size_t)row * 128 + (colx & 127);
              Cf[o] = vraw + (bias ? bias[colx & 127] : 0.0f);
            }
          } else {
            float v = vraw + (bias ? bias[colx] : 0.0f);
            if (do_relu) v = fmaxf(v, 0.0f);
            size_t o = (size_t)row * Nc + colx;
            if (Cf) Cf[o] = v;
            if (Ch) Ch[o] = f16_rne(v);
          }
        }
      }
    }
}

// ---------------------------------------------------------------------------
// GAT: wt[4][256] = {W@att_s(h0), W@att_s(h1), W@att_d(h0), W@att_d(h1)}
__global__ void k_wtilde(const float* __restrict__ gatW, const float* __restrict__ att_s,
                         const float* __restrict__ att_d, float* __restrict__ wt) {
  int k = threadIdx.x;
  const float* Wr = gatW + (size_t)k * 512;
  float s0 = 0, s1 = 0, d0 = 0, d1 = 0;
  for (int i = 0; i < 256; ++i) {
    float w0 = Wr[i], w1 = Wr[256 + i];
    s0 += w0 * att_s[i];       s1 += w1 * att_s[256 + i];
    d0 += w0 * att_d[i];       d1 += w1 * att_d[256 + i];
  }
  wt[k] = s0; wt[256 + k] = s1; wt[512 + k] = d0; wt[768 + k] = d1;
}

// per-node logits from xs fp16 plane
__global__ void k_al(const unsigned short* __restrict__ xsh_, const float* __restrict__ wt,
                     float* __restrict__ al_s, float* __restrict__ al_d) {
  int node = blockIdx.x * 4 + (threadIdx.x >> 6);
  int lane = threadIdx.x & 63;
  if (node >= NN) return;
  ushort4 hv = *(const ushort4*)(xsh_ + (size_t)node * 256 + lane * 4);
  float4 v = make_float4(h2f(hv.x), h2f(hv.y), h2f(hv.z), h2f(hv.w));
  const float4* w = (const float4*)wt;
  float4 a0 = w[lane], a1 = w[64 + lane], a2 = w[128 + lane], a3 = w[192 + lane];
  float s0 = v.x*a0.x + v.y*a0.y + v.z*a0.z + v.w*a0.w;
  float s1 = v.x*a1.x + v.y*a1.y + v.z*a1.z + v.w*a1.w;
  float s2 = v.x*a2.x + v.y*a2.y + v.z*a2.z + v.w*a2.w;
  float s3 = v.x*a3.x + v.y*a3.y + v.z*a3.z + v.w*a3.w;
  for (int off = 32; off; off >>= 1) {
    s0 += __shfl_down(s0, off); s1 += __shfl_down(s1, off);
    s2 += __shfl_down(s2, off); s3 += __shfl_down(s3, off);
  }
  if (lane == 0) {
    al_s[node*2] = s0; al_s[node*2 + 1] = s1;
    al_d[node*2] = s2; al_d[node*2 + 1] = s3;
  }
}

__device__ inline float lrelu(float v) { return v > 0.f ? v : 0.2f * v; }

// fused GAT softmax + aggregation over xs fp16 plane; writes AGG fp16 plane.
// [R9-proven form: 1 wave/node, 8B/lane.]
__global__ void k_gat_csr(const unsigned short* __restrict__ xsh_,
                          const int* __restrict__ rowptr, const int* __restrict__ srcs,
                          const float* __restrict__ als, const float* __restrict__ ald,
                          float2* __restrict__ es,
                          unsigned short* __restrict__ aggh) {
  int node = blockIdx.x * 4 + (threadIdx.x >> 6);
  int lane = threadIdx.x & 63;
  if (node >= NN) return;
  int p0 = rowptr[node], p1 = rowptr[node + 1];
  float bd0 = ald[node*2], bd1 = ald[node*2 + 1];
  float vs0 = lrelu(als[node*2] + bd0);
  float vs1 = lrelu(als[node*2 + 1] + bd1);

  // pass A: per-edge exp weight (computed once), streamed to es; denom partial
  float t0 = 0.f, t1 = 0.f;
  for (int p = p0 + lane; p < p1; p += 64) {
    int s = srcs[p];
    float2 a = *(const float2*)(als + (size_t)s * 2);
    float e0 = __expf(lrelu(a.x + bd0));
    float e1 = __expf(lrelu(a.y + bd1));
    es[p] = make_float2(e0, e1);
    t0 += e0; t1 += e1;
  }
  for (int off = 32; off; off >>= 1) {
    t0 += __shfl_xor(t0, off);
    t1 += __shfl_xor(t1, off);
  }
  float w0 = __expf(vs0), w1 = __expf(vs1);
  float den0 = t0 + w0, den1 = t1 + w1;
  __threadfence_block();   // drain es stores before cross-lane reads

  // pass B: aggregation: self + 8-way unrolled neighbor gather, FMA only
  ushort4 hv = *(const ushort4*)(xsh_ + (size_t)node * 256 + lane * 4);
  float4 v = make_float4(h2f(hv.x), h2f(hv.y), h2f(hv.z), h2f(hv.w));
  float4 acc0 = make_float4(w0*v.x, w0*v.y, w0*v.z, w0*v.w);
  float4 acc1 = make_float4(w1*v.x, w1*v.y, w1*v.z, w1*v.w);
  int p = p0;
  for (; p + 8 <= p1; p += 8) {
    int ss[8]; float2 ee[8]; ushort4 xr[8];
#pragma unroll
    for (int j = 0; j < 8; ++j) ss[j] = srcs[p + j];
#pragma unroll
    for (int j = 0; j < 8; ++j) ee[j] = es[p + j];
#pragma unroll
    for (int j = 0; j < 8; ++j)
      xr[j] = *(const ushort4*)(xsh_ + (size_t)ss[j] * 256 + lane * 4);
#pragma unroll
    for (int j = 0; j < 8; ++j) {
      float4 xv = make_float4(h2f(xr[j].x), h2f(xr[j].y), h2f(xr[j].z), h2f(xr[j].w));
      acc0.x += ee[j].x*xv.x; acc0.y += ee[j].x*xv.y;
      acc0.z += ee[j].x*xv.z; acc0.w += ee[j].x*xv.w;
      acc1.x += ee[j].y*xv.x; acc1.y += ee[j].y*xv.y;
      acc1.z += ee[j].y*xv.z; acc1.w += ee[j].y*xv.w;
    }
  }
  for (; p < p1; ++p) {
    int s = srcs[p];
    float2 e = es[p];
    ushort4 xh4 = *(const ushort4*)(xsh_ + (size_t)s * 256 + lane * 4);
    float4 xv = make_float4(h2f(xh4.x), h2f(xh4.y), h2f(xh4.z), h2f(xh4.w));
    acc0.x += e.x*xv.x; acc0.y += e.x*xv.y; acc0.z += e.x*xv.z; acc0.w += e.x*xv.w;
    acc1.x += e.y*xv.x; acc1.y += e.y*xv.y; acc1.z += e.y*xv.z; acc1.w += e.y*xv.w;
  }
  float i0 = 1.0f / fmaxf(den0, 1e-16f);
  float i1 = 1.0f / fmaxf(den1, 1e-16f);
  ushort4 h;
  size_t o = (size_t)node * 512 + lane * 4;
  h.x = f16_rne(acc0.x*i0); h.y = f16_rne(acc0.y*i0);
  h.z = f16_rne(acc0.z*i0); h.w = f16_rne(acc0.w*i0);
  *(ushort4*)(aggh + o) = h;
  h.x = f16_rne(acc1.x*i1); h.y = f16_rne(acc1.y*i1);
  h.z = f16_rne(acc1.z*i1); h.w = f16_rne(acc1.w*i1);
  *(ushort4*)(aggh + o + 256) = h;
}

// ---------------------------------------------------------------------------
// CSR RGCN aggregation. [R9-proven form] 1 wave/node, 8-way unrolled gather.
__global__ void k_rgcn_csr(const unsigned short* __restrict__ xth,
                           const int* __restrict__ rowptr, const int* __restrict__ srcs,
                           const int* __restrict__ ets, const int* __restrict__ cntrel,
                           const float* __restrict__ P3f,
                           unsigned short* __restrict__ oh) {
  int node = blockIdx.x * 4 + (threadIdx.x >> 6);
  int lane = threadIdx.x & 63;
  if (node >= NN) return;
  int p0 = rowptr[node], p1 = rowptr[node + 1];
  float inv0, inv1, inv2, inv3;
  {
    int4 c = ((const int4*)cntrel)[node];
    inv0 = c.x ? 1.0f/(float)c.x : 0.0f;  inv1 = c.y ? 1.0f/(float)c.y : 0.0f;
    inv2 = c.z ? 1.0f/(float)c.z : 0.0f;  inv3 = c.w ? 1.0f/(float)c.w : 0.0f;
  }
  float2 acc = ((const float2*)(P3f + ((size_t)node << 7)))[lane];
  int p = p0;
  for (; p + 8 <= p1; p += 8) {
    int ss[8], rr[8]; ushort2 xr[8];
#pragma unroll
    for (int j = 0; j < 8; ++j) { ss[j] = srcs[p + j]; rr[j] = ets[p + j]; }
#pragma unroll
    for (int j = 0; j < 8; ++j)
      xr[j] = *(const ushort2*)(xth + (((size_t)rr[j] * NN + ss[j]) << 7) + lane * 2);
#pragma unroll
    for (int j = 0; j < 8; ++j) {
      float w = (rr[j] == 0) ? inv0 : (rr[j] == 1) ? inv1 : (rr[j] == 2) ? inv2 : inv3;
      acc.x += h2f(xr[j].x) * w;
      acc.y += h2f(xr[j].y) * w;
    }
  }
  for (; p < p1; ++p) {
    int s = srcs[p], r = ets[p];
    ushort2 hv = *(const ushort2*)(xth + (((size_t)r * NN + s) << 7) + lane * 2);
    float w = (r == 0) ? inv0 : (r == 1) ? inv1 : (r == 2) ? inv2 : inv3;
    acc.x += h2f(hv.x) * w;
    acc.y += h2f(hv.y) * w;
  }
  ushort2 h;
  h.x = f16_rne(acc.x); h.y = f16_rne(acc.y);
  size_t o = ((size_t)node << 7) + lane * 2;
  *(ushort2*)(oh + o) = h;
}

// ---------------------------------------------------------------------------
__global__ void k_norm(float* __restrict__ out) {
  int gw = (int)(((long)blockIdx.x * blockDim.x + threadIdx.x) >> 6);
  int lane = threadIdx.x & 63;
  if (gw >= NN) return;
  float2* row = (float2*)(out + (size_t)gw * 128);
  float2 v = row[lane];
  float ss = v.x*v.x + v.y*v.y;
  for (int off = 32; off; off >>= 1) ss += __shfl_down(ss, off);
  ss = __shfl(ss, 0);
  float inv = 1.0f / fmaxf(sqrtf(ss), 1e-12f);
  row[lane] = make_float2(v.x*inv, v.y*inv);
}

// ---------------------------------------------------------------------------
extern "C" void kernel_launch(void* const* d_in, const int* in_sizes, int n_in,
                              void* d_out, int out_size, void* d_ws, size_t ws_size,
                              hipStream_t stream)
{
  const float* x     = (const float*)d_in[0];
  const int*   ei    = (const int*)d_in[1];
  const int*   etype = (const int*)d_in[2];
  const float* s1Wl  = (const float*)d_in[3];
  const float* s1Wr  = (const float*)d_in[4];
  const float* s1b   = (const float*)d_in[5];
  const float* s2Wl  = (const float*)d_in[6];
  const float* s2Wr  = (const float*)d_in[7];
  const float* s2b   = (const float*)d_in[8];
  const float* gatW  = (const float*)d_in[9];
  const float* att_s = (const float*)d_in[10];
  const float* att_d = (const float*)d_in[11];
  const float* gatb  = (const float*)d_in[12];
  const float* Wrel  = (const float*)d_in[13];
  const float* Wroot = (const float*)d_in[14];
  const float* rgcnb = (const float*)d_in[15];
  const float* fW    = (const float*)d_in[16];
  const float* fb    = (const float*)d_in[17];
  float* out = (float*)d_out;

  const int* src = ei;
  const int* dst = ei + NE;

  char* ws = (char*)d_ws;
  size_t off = 0;
  auto alloc = [&](size_t bytes) -> void* {
    void* p = ws + off;
    off = (off + bytes + 255) & ~(size_t)255;
    return p;
  };
  int*      deg    = (int*)alloc((size_t)NN * 4);        // kept for layout stability (unused)
  int*      cntrel = (int*)alloc((size_t)NN * NREL * 4);
  int*      rowptr = (int*)alloc((size_t)(NN + 1) * 4);
  int*      cursor = (int*)alloc((size_t)NN * 4);
  int*      bsum   = (int*)alloc((size_t)NB * 4);
  int*      boff   = (int*)alloc((size_t)NB * 4);
  int*      srcs   = (int*)alloc((size_t)NE * 4);
  int*      ets    = (int*)alloc((size_t)NE * 4);
  float*    al_s   = (float*)alloc((size_t)NN * 2 * 4);
  float*    al_d   = (float*)alloc((size_t)NN * 2 * 4);
  float*    wt     = (float*)alloc((size_t)4 * 256 * 4);
  unsigned short* PBh = (unsigned short*)alloc((size_t)PK_TOTAL * 8 * 2);
  // 4 x 51.2 MB slabs with strict lifetime overlay (total ws ~215 MB)
  char* SAb = (char*)alloc((size_t)NN * 1024);
  char* SBb = (char*)alloc((size_t)NN * 1024);
  char* SCb = (char*)alloc((size_t)NN * 1024);
  char* SDb = (char*)alloc((size_t)NN * 1024);
  (void)deg; (void)ws_size; (void)in_sizes; (void)n_in; (void)out_size;

  // SlabA: x/m1 fp16 planes -> aggh -> P3f + p3 fp16
  unsigned short* xh  = (unsigned short*)SAb;                   // N*128
  unsigned short* m1h = xh + (size_t)NN * 128;                  // N*128
  unsigned short* aggh = (unsigned short*)SAb;                  // N*512 (full slab)
  float*          P3f  = (float*)SAb;                           // N*128 f32
  unsigned short* p3h  = (unsigned short*)(SAb + (size_t)NN * 512);
  // SlabB: x1 fp16 -> xt fp16 (4 relations)
  unsigned short* x1h = (unsigned short*)SBb;                   // N*256
  unsigned short* xth = (unsigned short*)SBb;                   // 4*N*128
  // SlabC: m2 fp16 (dead after SAGE2 GEMM) -> es edge weights -> xg fp16
  unsigned short* m2h = (unsigned short*)SCb;                   // N*256
  float2*         es  = (float2*)SCb;                           // NE*8 = 6.4MB
  unsigned short* xgh = (unsigned short*)SCb;                   // N*256
  // SlabD: xs fp16 (persistent)
  unsigned short* xsh = (unsigned short*)SDb;                   // N*256

  const int NODEB = (NN + 3) / 4;
  const int GY = (NN + 127) / 128;

  // ---- weight packing + CSR build
  k_pack<<<(PK_TOTAL + 255) / 256, 256, 0, stream>>>(s1Wl, s1Wr, s2Wl, s2Wr, gatW, Wrel, Wroot, fW, PBh);
  hipMemsetAsync(cntrel, 0, (size_t)NN * NREL * 4, stream);
  hipMemsetAsync(cursor, 0, (size_t)NN * 4, stream);
  k_counts<<<(NE + 255) / 256, 256, 0, stream>>>(dst, etype, cntrel);
  k_scan1<<<NB, 256, 0, stream>>>(cntrel, bsum);
  k_scan2<<<1, 64, 0, stream>>>(bsum, boff, rowptr);
  k_scan3<<<NB, 256, 0, stream>>>(cntrel, boff, rowptr);
  k_fill<<<(NE + 255) / 256, 256, 0, stream>>>(src, dst, etype, rowptr, cursor, srcs, ets);
  k_split<<<((NN * 128 / 4) + 255) / 256, 256, 0, stream>>>(x, xh, (long)NN * 128 / 4);

  // ---- SAGE1: mean(x) -> m1 ; x1 = relu([m1|x]@[Wl;Wr]+b)
  k_mean128p<<<NODEB, 256, 0, stream>>>(xh, rowptr, srcs, m1h);
  k_gemm_mfma<<<dim3(2, GY, 1), 256, 0, stream>>>(PBh,
      m1h, 128, BF_S1WL, 128,  xh, 128, BF_S1WR, 128,  nullptr, 0, 0, 0,
      s1b, nullptr, x1h, NN, 256, 1.0f, 1, 0);

  // ---- SAGE2: mean(x1) -> m2 ; x_sage -> xs
  k_mean256p<<<NODEB, 256, 0, stream>>>(x1h, rowptr, srcs, m2h);
  k_gemm_mfma<<<dim3(2, GY, 1), 256, 0, stream>>>(PBh,
      m2h, 256, BF_S2WL, 256,  x1h, 256, BF_S2WR, 256,  nullptr, 0, 0, 0,
      s2b, nullptr, xsh, NN, 256, 1.0f, 1, 0);

  // ---- GAT: logits, fused softmax+aggregation (2-pass, es stream), projection
  k_wtilde<<<1, 256, 0, stream>>>(gatW, att_s, att_d, wt);
  k_al<<<NODEB, 256, 0, stream>>>(xsh, wt, al_s, al_d);
  k_gat_csr<<<NODEB, 256, 0, stream>>>(xsh, rowptr, srcs, al_s, al_d, es, aggh);
  k_gemm_mfma<<<dim3(2, GY, 1), 256, 0, stream>>>(PBh,
      aggh, 512, BF_GATW0, 256,  aggh + 256, 512, BF_GATW1, 256,  nullptr, 0, 0, 0,
      gatb, nullptr, xgh, NN, 256, 0.5f, 1, 0);

  // ---- RGCN: single fused GEMM (Nc=640 = WREL 512 cols + WROOT 128 cols):
  //      cols<512 scatter to xth, cols>=512 -> P3f with rgcnb bias.
  k_gemm_mfma<<<dim3(5, GY, 1), 256, 0, stream>>>(PBh,
      xgh, 256, BF_WREL, 256,  nullptr, 0, 0, 0,  nullptr, 0, 0, 0,
      rgcnb, P3f, xth, NN, 640, 1.0f, 0, 2);
  k_rgcn_csr<<<NODEB, 256, 0, stream>>>(xth, rowptr, srcs, ets, cntrel, P3f, p3h);

  // ---- fusion + L2 normalize
  k_gemm_mfma<<<dim3(1, GY, 1), 256, 0, stream>>>(PBh,
      xsh, 256, BF_FW0, 256,  xgh, 256, BF_FW1, 256,  p3h, 128, BF_FW2, 128,
      fb, out, nullptr, NN, 128, 1.0f, 0, 0);
  k_norm<<<(NN + 3) / 4, 256, 0, stream>>>(out);
}

// Round 14
// 684.684 us; speedup vs baseline: 1.1130x; 1.1130x over previous
//
#include <hip/hip_runtime.h>
#include <hip/hip_fp16.h>
#include <math.h>

constexpr int NN   = 50000;
constexpr int NE   = 800000;
constexpr int NREL = 4;
constexpr int NB   = (NN + 255) / 256;   // scan blocks

typedef _Float16 half8 __attribute__((ext_vector_type(8)));   // 8 fp16 (4 VGPRs)
typedef __attribute__((ext_vector_type(4))) float floatx4;    // MFMA acc

__device__ inline unsigned short f16_rne(float x) {
  return __half_as_ushort(__float2half_rn(x));
}
__device__ inline float h2f(unsigned short h) {
  return __half2float(__ushort_as_half(h));
}

// ---------------------------------------------------------------------------
__global__ void k_counts(const int* __restrict__ dst, const int* __restrict__ et,
                         int* cntrel) {
  int e = blockIdx.x * blockDim.x + threadIdx.x;
  if (e < NE) {
    int d = dst[e];
    atomicAdd(&cntrel[d * NREL + et[e]], 1);
  }
}

__global__ void k_scan1(const int* __restrict__ cntrel, int* bsum) {
  __shared__ int sm[256];
  int i = blockIdx.x * 256 + threadIdx.x;
  int v = 0;
  if (i < NN) { int4 c = ((const int4*)cntrel)[i]; v = c.x + c.y + c.z + c.w; }
  sm[threadIdx.x] = v;
  __syncthreads();
  for (int s = 128; s; s >>= 1) {
    if (threadIdx.x < s) sm[threadIdx.x] += sm[threadIdx.x + s];
    __syncthreads();
  }
  if (threadIdx.x == 0) bsum[blockIdx.x] = sm[0];
}
__global__ void k_scan2(const int* __restrict__ bsum, int* boff, int* rowptr) {
  if (threadIdx.x == 0 && blockIdx.x == 0) {
    int acc = 0;
    for (int b = 0; b < NB; ++b) { boff[b] = acc; acc += bsum[b]; }
    rowptr[NN] = NE;
  }
}
__global__ void k_scan3(const int* __restrict__ cntrel, const int* __restrict__ boff,
                        int* rowptr) {
  __shared__ int sm[256];
  int i = blockIdx.x * 256 + threadIdx.x;
  int v = 0;
  if (i < NN) { int4 c = ((const int4*)cntrel)[i]; v = c.x + c.y + c.z + c.w; }
  sm[threadIdx.x] = v;
  __syncthreads();
  for (int s = 1; s < 256; s <<= 1) {
    int t = (threadIdx.x >= s) ? sm[threadIdx.x - s] : 0;
    __syncthreads();
    sm[threadIdx.x] += t;
    __syncthreads();
  }
  if (i < NN) rowptr[i] = boff[blockIdx.x] + sm[threadIdx.x] - v;  // exclusive
}

__global__ void k_fill(const int* __restrict__ src, const int* __restrict__ dst,
                       const int* __restrict__ et, const int* __restrict__ rowptr,
                       int* cursor, int* srcs, int* ets) {
  int e = blockIdx.x * blockDim.x + threadIdx.x;
  if (e >= NE) return;
  int d = dst[e];
  int pos = rowptr[d] + atomicAdd(&cursor[d], 1);
  srcs[pos] = src[e];
  ets[pos]  = et[e];
}

// ---------------------------------------------------------------------------
// weight packing into MFMA fragment order, single fp16 plane (2^-11 rel err).
#define PK_N 14
__device__ __constant__ const int PK_BASE[PK_N]  = {0,1,2,3,4,4,5,5,5,5,6,7,7,7};
__device__ __constant__ const int PK_EOFF[PK_N]  = {0,0,0,0,0,256,0,32768,65536,98304,0,0,32768,65536};
__device__ __constant__ const int PK_K[PK_N]     = {128,128,256,256,256,256,256,256,256,256,256,256,256,128};
__device__ __constant__ const int PK_LDB[PK_N]   = {256,256,256,256,512,512,128,128,128,128,128,128,128,128};
__device__ __constant__ const int PK_START[PK_N] = {0,4096,8192,16384,24576,32768,40960,45056,49152,53248,57344,61440,65536,69632};
constexpr int PK_TOTAL = 71680;
constexpr int BF_S1WL = 0,     BF_S1WR = 4096,  BF_S2WL = 8192,  BF_S2WR = 16384;
constexpr int BF_GATW0 = 24576, BF_GATW1 = 32768, BF_WREL = 40960, BF_WROOT = 57344;
constexpr int BF_FW0 = 61440,  BF_FW1 = 65536,  BF_FW2 = 69632;

__global__ void k_pack(const float* b0, const float* b1, const float* b2, const float* b3,
                       const float* b4, const float* b5, const float* b6, const float* b7,
                       unsigned short* __restrict__ Bh) {
  int f = blockIdx.x * 256 + threadIdx.x;
  if (f >= PK_TOTAL) return;
  int m = 0;
#pragma unroll
  for (int i = 1; i < PK_N; ++i) if (f >= PK_START[i]) m = i;
  const float* bases[8] = {b0,b1,b2,b3,b4,b5,b6,b7};
  int lf = f - PK_START[m];
  int K = PK_K[m], ldb = PK_LDB[m];
  int Kq16 = K << 1;
  int ntile = lf / Kq16;
  int rem = lf - ntile * Kq16;
  int kq = rem >> 4, c = rem & 15;
  const float* sp = bases[PK_BASE[m]] + PK_EOFF[m] + (size_t)(kq * 8) * ldb + ntile * 16 + c;
#pragma unroll
  for (int j = 0; j < 8; ++j)
    Bh[(size_t)f * 8 + j] = f16_rne(sp[(size_t)j * ldb]);
}

// x -> fp16 plane
__global__ void k_split(const float* __restrict__ x, unsigned short* __restrict__ xh,
                        long total4) {
  long i = (long)blockIdx.x * blockDim.x + threadIdx.x;
  if (i >= total4) return;
  float4 v = ((const float4*)x)[i];
  ushort4 h;
  h.x = f16_rne(v.x); h.y = f16_rne(v.y);
  h.z = f16_rne(v.z); h.w = f16_rne(v.w);
  ((ushort4*)xh)[i] = h;
}

// ---------------------------------------------------------------------------
// CSR mean, 128 ch. [R9-proven form] 1 wave/node, 4-way unrolled gather.
__global__ void k_mean128p(const unsigned short* __restrict__ ih, const int* __restrict__ rowptr,
                           const int* __restrict__ srcs,
                           unsigned short* __restrict__ oh) {
  int node = blockIdx.x * 4 + (threadIdx.x >> 6);
  int lane = threadIdx.x & 63;
  if (node >= NN) return;
  int p0 = rowptr[node], p1 = rowptr[node + 1];
  float2 acc = make_float2(0.f, 0.f);
  int p = p0;
  for (; p + 4 <= p1; p += 4) {
    int s0 = srcs[p], s1 = srcs[p+1], s2 = srcs[p+2], s3 = srcs[p+3];
    ushort2 v0 = ((const ushort2*)(ih + ((size_t)s0 << 7)))[lane];
    ushort2 v1 = ((const ushort2*)(ih + ((size_t)s1 << 7)))[lane];
    ushort2 v2 = ((const ushort2*)(ih + ((size_t)s2 << 7)))[lane];
    ushort2 v3 = ((const ushort2*)(ih + ((size_t)s3 << 7)))[lane];
    acc.x += (h2f(v0.x) + h2f(v1.x)) + (h2f(v2.x) + h2f(v3.x));
    acc.y += (h2f(v0.y) + h2f(v1.y)) + (h2f(v2.y) + h2f(v3.y));
  }
  for (; p < p1; ++p) {
    int s = srcs[p];
    ushort2 hv = ((const ushort2*)(ih + ((size_t)s << 7)))[lane];
    acc.x += h2f(hv.x); acc.y += h2f(hv.y);
  }
  float inv = (p1 > p0) ? 1.0f / (float)(p1 - p0) : 0.0f;
  ushort2 h;
  h.x = f16_rne(acc.x * inv); h.y = f16_rne(acc.y * inv);
  size_t o = ((size_t)node << 7) + lane * 2;
  *(ushort2*)(oh + o) = h;
}

// CSR mean, 256 ch. [R9-proven form] 1 wave/node, 8-way unrolled gather.
__global__ void k_mean256p(const unsigned short* __restrict__ ih, const int* __restrict__ rowptr,
                           const int* __restrict__ srcs,
                           unsigned short* __restrict__ oh) {
  int node = blockIdx.x * 4 + (threadIdx.x >> 6);
  int lane = threadIdx.x & 63;
  if (node >= NN) return;
  int p0 = rowptr[node], p1 = rowptr[node + 1];
  float4 acc = make_float4(0.f, 0.f, 0.f, 0.f);
  int p = p0;
  for (; p + 8 <= p1; p += 8) {
    int ss[8]; ushort4 xr[8];
#pragma unroll
    for (int j = 0; j < 8; ++j) ss[j] = srcs[p + j];
#pragma unroll
    for (int j = 0; j < 8; ++j)
      xr[j] = *(const ushort4*)(ih + ((size_t)ss[j] << 8) + lane * 4);
#pragma unroll
    for (int j = 0; j < 8; ++j) {
      acc.x += h2f(xr[j].x); acc.y += h2f(xr[j].y);
      acc.z += h2f(xr[j].z); acc.w += h2f(xr[j].w);
    }
  }
  for (; p < p1; ++p) {
    int s = srcs[p];
    ushort4 hv = *(const ushort4*)(ih + ((size_t)s << 8) + lane * 4);
    acc.x += h2f(hv.x); acc.y += h2f(hv.y);
    acc.z += h2f(hv.z); acc.w += h2f(hv.w);
  }
  float inv = (p1 > p0) ? 1.0f / (float)(p1 - p0) : 0.0f;
  ushort4 h;
  h.x = f16_rne(acc.x * inv); h.y = f16_rne(acc.y * inv);
  h.z = f16_rne(acc.z * inv); h.w = f16_rne(acc.w * inv);
  size_t o = ((size_t)node << 8) + lane * 4;
  *(ushort4*)(oh + o) = h;
}

// ---------------------------------------------------------------------------
// fp16 MFMA GEMM, staged BK=64 [R11 structure] + [R13] next-tile register
// prefetch: prologue loads tile 0; each iteration writes LDS from regs, then
// ISSUES the loads for tile kt+64 BEFORE the 32 MFMAs — next-tile global
// latency hides under current MFMAs (regs are dead after the LDS write, so
// zero extra registers). LDS-free variant (R12) regressed: without the LDS
// stage every MFMA pack depended on same-iteration global loads (MfmaUtil 7%).
// XCD-chunked bijective block swizzle (T1/m204) for A-stripe L2 reuse.
// xtmode=2 (fused RGCN): cols<512 -> xth[c>>7][row][c&127] fp16 scatter;
//                        cols>=512 -> P3f[row][c&127] f32 + bias.
__global__ __launch_bounds__(256)
void k_gemm_mfma(const unsigned short* __restrict__ Bph,
                 const unsigned short* A0, int lda0, int bf0, int K0,
                 const unsigned short* A1, int lda1, int bf1, int K1,
                 const unsigned short* A2, int lda2, int bf2, int K2,
                 const float* __restrict__ bias, float* Cf, unsigned short* Ch,
                 int M, int Nc, float scale, int do_relu, int xtmode)
{
  __shared__ short Ash[2][8*64*8], Bsh[2][8*64*8];
  const int tid  = threadIdx.x;
  const int lane = tid & 63;
  const int wv   = tid >> 6;
  const int wm   = wv >> 1, wn = wv & 1;
  // bijective XCD-chunked swizzle over the x-y grid
  const int nwg = gridDim.x * gridDim.y;
  const int d   = blockIdx.x + gridDim.x * blockIdx.y;
  const int q   = nwg >> 3, r = nwg & 7;
  const int xcd = d & 7, di = d >> 3;
  const int wg  = (xcd < r ? xcd * (q + 1) : r * (q + 1) + (xcd - r) * q) + di;
  const int row0 = (wg / gridDim.x) * 128;
  const int col0 = (wg % gridDim.x) * 128;

  floatx4 acc[4][4];
#pragma unroll
  for (int i = 0; i < 4; ++i)
#pragma unroll
    for (int j = 0; j < 4; ++j) acc[i][j] = 0;

  const int a_m = tid >> 1;
  const int a_h = tid & 1;

  const unsigned short* Aarr[3] = {A0, A1, A2};
  const int ldaArr[3] = {lda0, lda1, lda2};
  const int bfArr[3]  = {bf0, bf1, bf2};
  const int Karr[3]   = {K0, K1, K2};

  for (int p = 0; p < 3; ++p) {
    const int K = Karr[p];
    if (K == 0) continue;
    const int lda = ldaArr[p];
    const bool arow_ok = (row0 + a_m) < M;
    const unsigned short* Ar = Aarr[p] + (size_t)(row0 + a_m) * lda + a_h * 16;
    const int Kq16 = K << 1;
    const int b_nt = tid >> 5;
    const int b_rem = (tid << 1) & 63;
    const int bbase = bfArr[p] + (col0 >> 4) * Kq16 + b_nt * Kq16 + b_rem;

    // prologue: load tile kt=0 into regs
    half8 a00, a01, a10, a11, b00, b01, b10, b11;
    {
      if (arow_ok) {
        a00 = *(const half8*)(const void*)(Ar + 0);
        a01 = *(const half8*)(const void*)(Ar + 8);
        a10 = *(const half8*)(const void*)(Ar + 32);
        a11 = *(const half8*)(const void*)(Ar + 40);
      } else {
#pragma unroll
        for (int i = 0; i < 8; ++i) {
          a00[i] = (_Float16)0; a01[i] = (_Float16)0;
          a10[i] = (_Float16)0; a11[i] = (_Float16)0;
        }
      }
      const size_t boff0 = (size_t)bbase * 8;
      b00 = *(const half8*)(const void*)(Bph + boff0);
      b01 = *(const half8*)(const void*)(Bph + boff0 + 8);
      b10 = *(const half8*)(const void*)(Bph + boff0 + 512);
      b11 = *(const half8*)(const void*)(Bph + boff0 + 520);
    }

    for (int kt = 0; kt < K; kt += 64) {
      __syncthreads();
      {
        int q2 = a_h * 2;
        int i0 = ((a_m >> 4) * 64 + ((a_m & 15) | (q2 << 4))) * 8;
        int i1 = ((a_m >> 4) * 64 + ((a_m & 15) | ((q2 + 1) << 4))) * 8;
        *(half8*)(void*)&Ash[0][i0] = a00;  *(half8*)(void*)&Ash[0][i1] = a01;
        *(half8*)(void*)&Ash[1][i0] = a10;  *(half8*)(void*)&Ash[1][i1] = a11;
      }
      {
        int f0 = tid * 2;
        *(half8*)(void*)&Bsh[0][(size_t)f0 * 8] = b00;
        *(half8*)(void*)&Bsh[0][(size_t)(f0 + 1) * 8] = b01;
        *(half8*)(void*)&Bsh[1][(size_t)f0 * 8] = b10;
        *(half8*)(void*)&Bsh[1][(size_t)(f0 + 1) * 8] = b11;
      }
      __syncthreads();

      // issue next-tile loads BEFORE the MFMAs (latency hides under compute)
      int ktn = kt + 64;
      if (ktn < K) {
        if (arow_ok) {
          a00 = *(const half8*)(const void*)(Ar + ktn);
          a01 = *(const half8*)(const void*)(Ar + ktn + 8);
          a10 = *(const half8*)(const void*)(Ar + ktn + 32);
          a11 = *(const half8*)(const void*)(Ar + ktn + 40);
        }
        const size_t boffn = (size_t)(bbase + (ktn << 1)) * 8;
        b00 = *(const half8*)(const void*)(Bph + boffn);
        b01 = *(const half8*)(const void*)(Bph + boffn + 8);
        b10 = *(const half8*)(const void*)(Bph + boffn + 512);
        b11 = *(const half8*)(const void*)(Bph + boffn + 520);
      }

#pragma unroll
      for (int s = 0; s < 2; ++s) {
        half8 afh[4], bfh[4];
#pragma unroll
        for (int mt = 0; mt < 4; ++mt) {
          int idx = ((wm * 4 + mt) * 64 + lane) * 8;
          afh[mt] = *(half8*)(void*)&Ash[s][idx];
        }
#pragma unroll
        for (int nt = 0; nt < 4; ++nt) {
          int idx = ((wn * 4 + nt) * 64 + lane) * 8;
          bfh[nt] = *(half8*)(void*)&Bsh[s][idx];
        }
#pragma unroll
        for (int mt = 0; mt < 4; ++mt)
#pragma unroll
          for (int nt = 0; nt < 4; ++nt)
            acc[mt][nt] = __builtin_amdgcn_mfma_f32_16x16x32_f16(afh[mt], bfh[nt], acc[mt][nt], 0, 0, 0);
      }
    }
  }

  // epilogue: C/D layout col=lane&15, row=(lane>>4)*4+reg   [m89-verified]
  const int cl = lane & 15;
  const int rq = lane >> 4;
#pragma unroll
  for (int mt = 0; mt < 4; ++mt)
#pragma unroll
    for (int r2 = 0; r2 < 4; ++r2) {
      int row = row0 + wm * 64 + mt * 16 + rq * 4 + r2;
      if (row < M) {
#pragma unroll
        for (int nt = 0; nt < 4; ++nt) {
          int colx = col0 + wn * 64 + nt * 16 + cl;
          float vraw = acc[mt][nt][r2] * scale;
          if (xtmode == 2) {
            // fused RGCN: WREL cols [0,512) scatter to xth; WROOT cols [512,640) -> P3f
            if (colx < 512) {
              size_t o = (size_t)(colx >> 7) * ((size_t)NN * 128) + (size_t)row * 128 + (colx & 127);
              Ch[o] = f16_rne(vraw);
            } else {
              size_t o = (size_t)row * 128 + (colx & 127);
              Cf[o] = vraw + (bias ? bias[colx & 127] : 0.0f);
            }
          } else {
            float v = vraw + (bias ? bias[colx] : 0.0f);
            if (do_relu) v = fmaxf(v, 0.0f);
            size_t o = (size_t)row * Nc + colx;
            if (Cf) Cf[o] = v;
            if (Ch) Ch[o] = f16_rne(v);
          }
        }
      }
    }
}

// ---------------------------------------------------------------------------
// GAT: wt[4][256] = {W@att_s(h0), W@att_s(h1), W@att_d(h0), W@att_d(h1)}
__global__ void k_wtilde(const float* __restrict__ gatW, const float* __restrict__ att_s,
                         const float* __restrict__ att_d, float* __restrict__ wt) {
  int k = threadIdx.x;
  const float* Wr = gatW + (size_t)k * 512;
  float s0 = 0, s1 = 0, d0 = 0, d1 = 0;
  for (int i = 0; i < 256; ++i) {
    float w0 = Wr[i], w1 = Wr[256 + i];
    s0 += w0 * att_s[i];       s1 += w1 * att_s[256 + i];
    d0 += w0 * att_d[i];       d1 += w1 * att_d[256 + i];
  }
  wt[k] = s0; wt[256 + k] = s1; wt[512 + k] = d0; wt[768 + k] = d1;
}

// per-node logits from xs fp16 plane
__global__ void k_al(const unsigned short* __restrict__ xsh_, const float* __restrict__ wt,
                     float* __restrict__ al_s, float* __restrict__ al_d) {
  int node = blockIdx.x * 4 + (threadIdx.x >> 6);
  int lane = threadIdx.x & 63;
  if (node >= NN) return;
  ushort4 hv = *(const ushort4*)(xsh_ + (size_t)node * 256 + lane * 4);
  float4 v = make_float4(h2f(hv.x), h2f(hv.y), h2f(hv.z), h2f(hv.w));
  const float4* w = (const float4*)wt;
  float4 a0 = w[lane], a1 = w[64 + lane], a2 = w[128 + lane], a3 = w[192 + lane];
  float s0 = v.x*a0.x + v.y*a0.y + v.z*a0.z + v.w*a0.w;
  float s1 = v.x*a1.x + v.y*a1.y + v.z*a1.z + v.w*a1.w;
  float s2 = v.x*a2.x + v.y*a2.y + v.z*a2.z + v.w*a2.w;
  float s3 = v.x*a3.x + v.y*a3.y + v.z*a3.z + v.w*a3.w;
  for (int off = 32; off; off >>= 1) {
    s0 += __shfl_down(s0, off); s1 += __shfl_down(s1, off);
    s2 += __shfl_down(s2, off); s3 += __shfl_down(s3, off);
  }
  if (lane == 0) {
    al_s[node*2] = s0; al_s[node*2 + 1] = s1;
    al_d[node*2] = s2; al_d[node*2 + 1] = s3;
  }
}

__device__ inline float lrelu(float v) { return v > 0.f ? v : 0.2f * v; }

// fused GAT softmax + aggregation over xs fp16 plane; writes AGG fp16 plane.
// [R9-proven form: 1 wave/node, 8B/lane.]
__global__ void k_gat_csr(const unsigned short* __restrict__ xsh_,
                          const int* __restrict__ rowptr, const int* __restrict__ srcs,
                          const float* __restrict__ als, const float* __restrict__ ald,
                          float2* __restrict__ es,
                          unsigned short* __restrict__ aggh) {
  int node = blockIdx.x * 4 + (threadIdx.x >> 6);
  int lane = threadIdx.x & 63;
  if (node >= NN) return;
  int p0 = rowptr[node], p1 = rowptr[node + 1];
  float bd0 = ald[node*2], bd1 = ald[node*2 + 1];
  float vs0 = lrelu(als[node*2] + bd0);
  float vs1 = lrelu(als[node*2 + 1] + bd1);

  // pass A: per-edge exp weight (computed once), streamed to es; denom partial
  float t0 = 0.f, t1 = 0.f;
  for (int p = p0 + lane; p < p1; p += 64) {
    int s = srcs[p];
    float2 a = *(const float2*)(als + (size_t)s * 2);
    float e0 = __expf(lrelu(a.x + bd0));
    float e1 = __expf(lrelu(a.y + bd1));
    es[p] = make_float2(e0, e1);
    t0 += e0; t1 += e1;
  }
  for (int off = 32; off; off >>= 1) {
    t0 += __shfl_xor(t0, off);
    t1 += __shfl_xor(t1, off);
  }
  float w0 = __expf(vs0), w1 = __expf(vs1);
  float den0 = t0 + w0, den1 = t1 + w1;
  __threadfence_block();   // drain es stores before cross-lane reads

  // pass B: aggregation: self + 8-way unrolled neighbor gather, FMA only
  ushort4 hv = *(const ushort4*)(xsh_ + (size_t)node * 256 + lane * 4);
  float4 v = make_float4(h2f(hv.x), h2f(hv.y), h2f(hv.z), h2f(hv.w));
  float4 acc0 = make_float4(w0*v.x, w0*v.y, w0*v.z, w0*v.w);
  float4 acc1 = make_float4(w1*v.x, w1*v.y, w1*v.z, w1*v.w);
  int p = p0;
  for (; p + 8 <= p1; p += 8) {
    int ss[8]; float2 ee[8]; ushort4 xr[8];
#pragma unroll
    for (int j = 0; j < 8; ++j) ss[j] = srcs[p + j];
#pragma unroll
    for (int j = 0; j < 8; ++j) ee[j] = es[p + j];
#pragma unroll
    for (int j = 0; j < 8; ++j)
      xr[j] = *(const ushort4*)(xsh_ + (size_t)ss[j] * 256 + lane * 4);
#pragma unroll
    for (int j = 0; j < 8; ++j) {
      float4 xv = make_float4(h2f(xr[j].x), h2f(xr[j].y), h2f(xr[j].z), h2f(xr[j].w));
      acc0.x += ee[j].x*xv.x; acc0.y += ee[j].x*xv.y;
      acc0.z += ee[j].x*xv.z; acc0.w += ee[j].x*xv.w;
      acc1.x += ee[j].y*xv.x; acc1.y += ee[j].y*xv.y;
      acc1.z += ee[j].y*xv.z; acc1.w += ee[j].y*xv.w;
    }
  }
  for (; p < p1; ++p) {
    int s = srcs[p];
    float2 e = es[p];
    ushort4 xh4 = *(const ushort4*)(xsh_ + (size_t)s * 256 + lane * 4);
    float4 xv = make_float4(h2f(xh4.x), h2f(xh4.y), h2f(xh4.z), h2f(xh4.w));
    acc0.x += e.x*xv.x; acc0.y += e.x*xv.y; acc0.z += e.x*xv.z; acc0.w += e.x*xv.w;
    acc1.x += e.y*xv.x; acc1.y += e.y*xv.y; acc1.z += e.y*xv.z; acc1.w += e.y*xv.w;
  }
  float i0 = 1.0f / fmaxf(den0, 1e-16f);
  float i1 = 1.0f / fmaxf(den1, 1e-16f);
  ushort4 h;
  size_t o = (size_t)node * 512 + lane * 4;
  h.x = f16_rne(acc0.x*i0); h.y = f16_rne(acc0.y*i0);
  h.z = f16_rne(acc0.z*i0); h.w = f16_rne(acc0.w*i0);
  *(ushort4*)(aggh + o) = h;
  h.x = f16_rne(acc1.x*i1); h.y = f16_rne(acc1.y*i1);
  h.z = f16_rne(acc1.z*i1); h.w = f16_rne(acc1.w*i1);
  *(ushort4*)(aggh + o + 256) = h;
}

// ---------------------------------------------------------------------------
// CSR RGCN aggregation. [R9-proven form] 1 wave/node, 8-way unrolled gather.
__global__ void k_rgcn_csr(const unsigned short* __restrict__ xth,
                           const int* __restrict__ rowptr, const int* __restrict__ srcs,
                           const int* __restrict__ ets, const int* __restrict__ cntrel,
                           const float* __restrict__ P3f,
                           unsigned short* __restrict__ oh) {
  int node = blockIdx.x * 4 + (threadIdx.x >> 6);
  int lane = threadIdx.x & 63;
  if (node >= NN) return;
  int p0 = rowptr[node], p1 = rowptr[node + 1];
  float inv0, inv1, inv2, inv3;
  {
    int4 c = ((const int4*)cntrel)[node];
    inv0 = c.x ? 1.0f/(float)c.x : 0.0f;  inv1 = c.y ? 1.0f/(float)c.y : 0.0f;
    inv2 = c.z ? 1.0f/(float)c.z : 0.0f;  inv3 = c.w ? 1.0f/(float)c.w : 0.0f;
  }
  float2 acc = ((const float2*)(P3f + ((size_t)node << 7)))[lane];
  int p = p0;
  for (; p + 8 <= p1; p += 8) {
    int ss[8], rr[8]; ushort2 xr[8];
#pragma unroll
    for (int j = 0; j < 8; ++j) { ss[j] = srcs[p + j]; rr[j] = ets[p + j]; }
#pragma unroll
    for (int j = 0; j < 8; ++j)
      xr[j] = *(const ushort2*)(xth + (((size_t)rr[j] * NN + ss[j]) << 7) + lane * 2);
#pragma unroll
    for (int j = 0; j < 8; ++j) {
      float w = (rr[j] == 0) ? inv0 : (rr[j] == 1) ? inv1 : (rr[j] == 2) ? inv2 : inv3;
      acc.x += h2f(xr[j].x) * w;
      acc.y += h2f(xr[j].y) * w;
    }
  }
  for (; p < p1; ++p) {
    int s = srcs[p], r = ets[p];
    ushort2 hv = *(const ushort2*)(xth + (((size_t)r * NN + s) << 7) + lane * 2);
    float w = (r == 0) ? inv0 : (r == 1) ? inv1 : (r == 2) ? inv2 : inv3;
    acc.x += h2f(hv.x) * w;
    acc.y += h2f(hv.y) * w;
  }
  ushort2 h;
  h.x = f16_rne(acc.x); h.y = f16_rne(acc.y);
  size_t o = ((size_t)node << 7) + lane * 2;
  *(ushort2*)(oh + o) = h;
}

// ---------------------------------------------------------------------------
__global__ void k_norm(float* __restrict__ out) {
  int gw = (int)(((long)blockIdx.x * blockDim.x + threadIdx.x) >> 6);
  int lane = threadIdx.x & 63;
  if (gw >= NN) return;
  float2* row = (float2*)(out + (size_t)gw * 128);
  float2 v = row[lane];
  float ss = v.x*v.x + v.y*v.y;
  for (int off = 32; off; off >>= 1) ss += __shfl_down(ss, off);
  ss = __shfl(ss, 0);
  float inv = 1.0f / fmaxf(sqrtf(ss), 1e-12f);
  row[lane] = make_float2(v.x*inv, v.y*inv);
}

// ---------------------------------------------------------------------------
extern "C" void kernel_launch(void* const* d_in, const int* in_sizes, int n_in,
                              void* d_out, int out_size, void* d_ws, size_t ws_size,
                              hipStream_t stream)
{
  const float* x     = (const float*)d_in[0];
  const int*   ei    = (const int*)d_in[1];
  const int*   etype = (const int*)d_in[2];
  const float* s1Wl  = (const float*)d_in[3];
  const float* s1Wr  = (const float*)d_in[4];
  const float* s1b   = (const float*)d_in[5];
  const float* s2Wl  = (const float*)d_in[6];
  const float* s2Wr  = (const float*)d_in[7];
  const float* s2b   = (const float*)d_in[8];
  const float* gatW  = (const float*)d_in[9];
  const float* att_s = (const float*)d_in[10];
  const float* att_d = (const float*)d_in[11];
  const float* gatb  = (const float*)d_in[12];
  const float* Wrel  = (const float*)d_in[13];
  const float* Wroot = (const float*)d_in[14];
  const float* rgcnb = (const float*)d_in[15];
  const float* fW    = (const float*)d_in[16];
  const float* fb    = (const float*)d_in[17];
  float* out = (float*)d_out;

  const int* src = ei;
  const int* dst = ei + NE;

  char* ws = (char*)d_ws;
  size_t off = 0;
  auto alloc = [&](size_t bytes) -> void* {
    void* p = ws + off;
    off = (off + bytes + 255) & ~(size_t)255;
    return p;
  };
  int*      deg    = (int*)alloc((size_t)NN * 4);        // kept for layout stability (unused)
  int*      cntrel = (int*)alloc((size_t)NN * NREL * 4);
  int*      rowptr = (int*)alloc((size_t)(NN + 1) * 4);
  int*      cursor = (int*)alloc((size_t)NN * 4);
  int*      bsum   = (int*)alloc((size_t)NB * 4);
  int*      boff   = (int*)alloc((size_t)NB * 4);
  int*      srcs   = (int*)alloc((size_t)NE * 4);
  int*      ets    = (int*)alloc((size_t)NE * 4);
  float*    al_s   = (float*)alloc((size_t)NN * 2 * 4);
  float*    al_d   = (float*)alloc((size_t)NN * 2 * 4);
  float*    wt     = (float*)alloc((size_t)4 * 256 * 4);
  unsigned short* PBh = (unsigned short*)alloc((size_t)PK_TOTAL * 8 * 2);
  // 4 x 51.2 MB slabs with strict lifetime overlay (total ws ~215 MB)
  char* SAb = (char*)alloc((size_t)NN * 1024);
  char* SBb = (char*)alloc((size_t)NN * 1024);
  char* SCb = (char*)alloc((size_t)NN * 1024);
  char* SDb = (char*)alloc((size_t)NN * 1024);
  (void)deg; (void)ws_size; (void)in_sizes; (void)n_in; (void)out_size;

  // SlabA: x/m1 fp16 planes -> aggh -> P3f + p3 fp16
  unsigned short* xh  = (unsigned short*)SAb;                   // N*128
  unsigned short* m1h = xh + (size_t)NN * 128;                  // N*128
  unsigned short* aggh = (unsigned short*)SAb;                  // N*512 (full slab)
  float*          P3f  = (float*)SAb;                           // N*128 f32
  unsigned short* p3h  = (unsigned short*)(SAb + (size_t)NN * 512);
  // SlabB: x1 fp16 -> xt fp16 (4 relations)
  unsigned short* x1h = (unsigned short*)SBb;                   // N*256
  unsigned short* xth = (unsigned short*)SBb;                   // 4*N*128
  // SlabC: m2 fp16 (dead after SAGE2 GEMM) -> es edge weights -> xg fp16
  unsigned short* m2h = (unsigned short*)SCb;                   // N*256
  float2*         es  = (float2*)SCb;                           // NE*8 = 6.4MB
  unsigned short* xgh = (unsigned short*)SCb;                   // N*256
  // SlabD: xs fp16 (persistent)
  unsigned short* xsh = (unsigned short*)SDb;                   // N*256

  const int NODEB = (NN + 3) / 4;
  const int GY = (NN + 127) / 128;

  // ---- weight packing + CSR build
  k_pack<<<(PK_TOTAL + 255) / 256, 256, 0, stream>>>(s1Wl, s1Wr, s2Wl, s2Wr, gatW, Wrel, Wroot, fW, PBh);
  hipMemsetAsync(cntrel, 0, (size_t)NN * NREL * 4, stream);
  hipMemsetAsync(cursor, 0, (size_t)NN * 4, stream);
  k_counts<<<(NE + 255) / 256, 256, 0, stream>>>(dst, etype, cntrel);
  k_scan1<<<NB, 256, 0, stream>>>(cntrel, bsum);
  k_scan2<<<1, 64, 0, stream>>>(bsum, boff, rowptr);
  k_scan3<<<NB, 256, 0, stream>>>(cntrel, boff, rowptr);
  k_fill<<<(NE + 255) / 256, 256, 0, stream>>>(src, dst, etype, rowptr, cursor, srcs, ets);
  k_split<<<((NN * 128 / 4) + 255) / 256, 256, 0, stream>>>(x, xh, (long)NN * 128 / 4);

  // ---- SAGE1: mean(x) -> m1 ; x1 = relu([m1|x]@[Wl;Wr]+b)
  k_mean128p<<<NODEB, 256, 0, stream>>>(xh, rowptr, srcs, m1h);
  k_gemm_mfma<<<dim3(2, GY, 1), 256, 0, stream>>>(PBh,
      m1h, 128, BF_S1WL, 128,  xh, 128, BF_S1WR, 128,  nullptr, 0, 0, 0,
      s1b, nullptr, x1h, NN, 256, 1.0f, 1, 0);

  // ---- SAGE2: mean(x1) -> m2 ; x_sage -> xs
  k_mean256p<<<NODEB, 256, 0, stream>>>(x1h, rowptr, srcs, m2h);
  k_gemm_mfma<<<dim3(2, GY, 1), 256, 0, stream>>>(PBh,
      m2h, 256, BF_S2WL, 256,  x1h, 256, BF_S2WR, 256,  nullptr, 0, 0, 0,
      s2b, nullptr, xsh, NN, 256, 1.0f, 1, 0);

  // ---- GAT: logits, fused softmax+aggregation (2-pass, es stream), projection
  k_wtilde<<<1, 256, 0, stream>>>(gatW, att_s, att_d, wt);
  k_al<<<NODEB, 256, 0, stream>>>(xsh, wt, al_s, al_d);
  k_gat_csr<<<NODEB, 256, 0, stream>>>(xsh, rowptr, srcs, al_s, al_d, es, aggh);
  k_gemm_mfma<<<dim3(2, GY, 1), 256, 0, stream>>>(PBh,
      aggh, 512, BF_GATW0, 256,  aggh + 256, 512, BF_GATW1, 256,  nullptr, 0, 0, 0,
      gatb, nullptr, xgh, NN, 256, 0.5f, 1, 0);

  // ---- RGCN: single fused GEMM (Nc=640 = WREL 512 cols + WROOT 128 cols):
  //      cols<512 scatter to xth, cols>=512 -> P3f with rgcnb bias.
  k_gemm_mfma<<<dim3(5, GY, 1), 256, 0, stream>>>(PBh,
      xgh, 256, BF_WREL, 256,  nullptr, 0, 0, 0,  nullptr, 0, 0, 0,
      rgcnb, P3f, xth, NN, 640, 1.0f, 0, 2);
  k_rgcn_csr<<<NODEB, 256, 0, stream>>>(xth, rowptr, srcs, ets, cntrel, P3f, p3h);

  // ---- fusion + L2 normalize
  k_gemm_mfma<<<dim3(1, GY, 1), 256, 0, stream>>>(PBh,
      xsh, 256, BF_FW0, 256,  xgh, 256, BF_FW1, 256,  p3h, 128, BF_FW2, 128,
      fb, out, nullptr, NN, 128, 1.0f, 0, 0);
  k_norm<<<(NN + 3) / 4, 256, 0, stream>>>(out);
}